// Round 2
// baseline (197.013 us; speedup 1.0000x reference)
//
#include <hip/hip_runtime.h>
#include <hip/hip_bf16.h>

// SparseAttentionHead on MI355X.
// out[i,c] = elu( sum_j P[i,j] * F[j,c] / Z[i] ),
//   P[i,j] = exp( adj[i,j] * lrelu(a1[i]+a2[j]) )   (adj in {0,1}; exp(0)=1 for adj=0)
//   Z[i]   = sum_j P[i,j]
// No max-subtraction: a1+a2 ~ N(0,2), max ~6 -> exp safe in fp32.
//
// K2 v2: no barriers in hot loop. Each wave builds MFMA A-fragments in
// registers straight from adj (lane l: row l&15, k = 8*(l>>4)+0..7), K split
// across the block's 4 waves, LDS used once for the final partial reduction.

typedef short bf16x8 __attribute__((ext_vector_type(8)));
typedef float f32x4 __attribute__((ext_vector_type(4)));

static __device__ __forceinline__ short f2bf(float f) {
  union { float f; unsigned u; } v; v.f = f;
  unsigned r = v.u + 0x7fffu + ((v.u >> 16) & 1u);
  return (short)(r >> 16);
}

// K1: seq_fts = W1 @ x (fp32), store FT[c][n] = bf16(seq_fts), accumulate a1/a2.
__global__ __launch_bounds__(256) void k1_seqfts(
    const float* __restrict__ x, const float* __restrict__ W1,
    const float* __restrict__ wf1, const float* __restrict__ wf2,
    short* __restrict__ FT, float* __restrict__ a1, float* __restrict__ a2) {
  const int cb = blockIdx.x & 7;
  const int nb = blockIdx.x >> 3;
  const int n = nb * 256 + threadIdx.x;
  float acc[16];
#pragma unroll
  for (int i = 0; i < 16; ++i) acc[i] = 0.f;
  const float* wrow = W1 + cb * 16 * 128;
#pragma unroll 4
  for (int c = 0; c < 128; ++c) {
    float xv = x[c * 8192 + n];
#pragma unroll
    for (int cc = 0; cc < 16; ++cc) acc[cc] = fmaf(wrow[cc * 128 + c], xv, acc[cc]);
  }
  float p1 = 0.f, p2 = 0.f;
#pragma unroll
  for (int cc = 0; cc < 16; ++cc) {
    int co = cb * 16 + cc;
    FT[co * 8192 + n] = f2bf(acc[cc]);
    p1 = fmaf(wf1[co], acc[cc], p1);
    p2 = fmaf(wf2[co], acc[cc], p2);
  }
  atomicAdd(&a1[n], p1);
  atomicAdd(&a2[n], p2);
}

// K2: grid 512 (16 rows/block), 256 threads = 4 waves. Wave w handles
// k in [w*2048, (w+1)*2048) over 64 steps of 32. Per step: A-frag from adj
// in registers, 8 B-frags from FT, 8 MFMAs. End: LDS reduce + elu epilogue.
__global__ __launch_bounds__(256, 2) void k2_attn(
    const float* __restrict__ adj, const short* __restrict__ FT,
    const float* __restrict__ a1, const float* __restrict__ a2,
    const float* __restrict__ b1p, const float* __restrict__ b2p,
    float* __restrict__ out) {
  __shared__ float part[4 * 16 * 128];   // [wave][row][col], 32 KB
  __shared__ float zpart[4][16];
  const int t = threadIdx.x;
  const int l = t & 63;
  const int w = t >> 6;
  const int r = l & 15;        // A row / B col within 16
  const int kg = l >> 4;       // k-subgroup: 8 elems at 8*kg
  const int i0 = blockIdx.x * 16;
  const float af = a1[i0 + r] + b1p[0] + b2p[0];

  const int kb = w * 2048 + kg * 8;
  const float* adjp = adj + (size_t)(i0 + r) * 8192 + kb;
  const float* a2p  = a2 + kb;
  const short* ftr  = FT + (size_t)r * 8192 + kb;   // + cb*131072 + ko per frag

  f32x4 acc[8];
#pragma unroll
  for (int cb = 0; cb < 8; ++cb) acc[cb] = f32x4{0.f, 0.f, 0.f, 0.f};
  float zacc = 0.f;

  auto STEP = [&](int ko, f32x4 av0, f32x4 av1, f32x4 q0, f32x4 q1) {
    bf16x8 b[8];
#pragma unroll
    for (int cb = 0; cb < 8; ++cb)
      b[cb] = *(const bf16x8*)(ftr + cb * 131072 + ko);   // issued before exp chain
    bf16x8 afr;
#pragma unroll
    for (int j = 0; j < 4; ++j) {
      float tt = af + q0[j];
      float lr = fmaxf(tt, 0.01f * tt);
      float p = __expf(av0[j] * lr);
      zacc += p;
      afr[j] = f2bf(p);
    }
#pragma unroll
    for (int j = 0; j < 4; ++j) {
      float tt = af + q1[j];
      float lr = fmaxf(tt, 0.01f * tt);
      float p = __expf(av1[j] * lr);
      zacc += p;
      afr[4 + j] = f2bf(p);
    }
#pragma unroll
    for (int cb = 0; cb < 8; ++cb)
      acc[cb] = __builtin_amdgcn_mfma_f32_16x16x32_bf16(afr, b[cb], acc[cb], 0, 0, 0);
  };

  // 2-deep named-register prefetch of adj + a2 (no barriers -> survives).
  f32x4 avA0 = *(const f32x4*)(adjp);
  f32x4 avA1 = *(const f32x4*)(adjp + 4);
  f32x4 qA0  = *(const f32x4*)(a2p);
  f32x4 qA1  = *(const f32x4*)(a2p + 4);
  f32x4 avB0 = *(const f32x4*)(adjp + 32);
  f32x4 avB1 = *(const f32x4*)(adjp + 36);
  f32x4 qB0  = *(const f32x4*)(a2p + 32);
  f32x4 qB1  = *(const f32x4*)(a2p + 36);

  for (int s = 0; s < 64; s += 2) {
    f32x4 cA0 = avA0, cA1 = avA1, d0 = qA0, d1 = qA1;
    if (s + 2 < 64) {
      avA0 = *(const f32x4*)(adjp + (s + 2) * 32);
      avA1 = *(const f32x4*)(adjp + (s + 2) * 32 + 4);
      qA0  = *(const f32x4*)(a2p + (s + 2) * 32);
      qA1  = *(const f32x4*)(a2p + (s + 2) * 32 + 4);
    }
    STEP(s * 32, cA0, cA1, d0, d1);
    f32x4 cB0 = avB0, cB1 = avB1, e0v = qB0, e1v = qB1;
    if (s + 3 < 64) {
      avB0 = *(const f32x4*)(adjp + (s + 3) * 32);
      avB1 = *(const f32x4*)(adjp + (s + 3) * 32 + 4);
      qB0  = *(const f32x4*)(a2p + (s + 3) * 32);
      qB1  = *(const f32x4*)(a2p + (s + 3) * 32 + 4);
    }
    STEP((s + 1) * 32, cB0, cB1, e0v, e1v);
  }

  // Z across the 4 lanes sharing a row (l, l^16, l^32, l^48).
  zacc += __shfl_xor(zacc, 16);
  zacc += __shfl_xor(zacc, 32);
  if (kg == 0) zpart[w][r] = zacc;

  // Store partials. C/D layout: col = l&15, row = 4*(l>>4)+q.
  float* pw = part + w * 2048;
#pragma unroll
  for (int cb = 0; cb < 8; ++cb) {
#pragma unroll
    for (int q = 0; q < 4; ++q)
      pw[(4 * kg + q) * 128 + cb * 16 + r] = acc[cb][q];
  }
  __syncthreads();

  // Reduce 4 partials, normalize, elu, store. 8 outputs per thread.
  const int e0 = t * 8;
  const int rr = e0 >> 7;
  float zs = zpart[0][rr] + zpart[1][rr] + zpart[2][rr] + zpart[3][rr];
  f32x4 v0 = f32x4{0.f, 0.f, 0.f, 0.f}, v1 = f32x4{0.f, 0.f, 0.f, 0.f};
#pragma unroll
  for (int ww = 0; ww < 4; ++ww) {
    v0 += *(const f32x4*)(part + ww * 2048 + e0);
    v1 += *(const f32x4*)(part + ww * 2048 + e0 + 4);
  }
  const float inv = 1.0f / zs;
  f32x4 o0, o1;
#pragma unroll
  for (int j = 0; j < 4; ++j) {
    float v = v0[j] * inv;
    o0[j] = v > 0.f ? v : __expf(v) - 1.f;
    v = v1[j] * inv;
    o1[j] = v > 0.f ? v : __expf(v) - 1.f;
  }
  *(f32x4*)(out + (size_t)i0 * 128 + e0) = o0;
  *(f32x4*)(out + (size_t)i0 * 128 + e0 + 4) = o1;
}

extern "C" void kernel_launch(void* const* d_in, const int* in_sizes, int n_in,
                              void* d_out, int out_size, void* d_ws, size_t ws_size,
                              hipStream_t stream) {
  const float* x   = (const float*)d_in[0];
  // d_in[1] = edge_index (unused by the reference computation)
  const float* adj = (const float*)d_in[2];
  const float* W1  = (const float*)d_in[3];
  const float* wf1 = (const float*)d_in[4];
  const float* b1  = (const float*)d_in[5];
  const float* wf2 = (const float*)d_in[6];
  const float* b2  = (const float*)d_in[7];
  float* out = (float*)d_out;

  short* FT = (short*)d_ws;                                    // 128*8192 bf16 = 2MB
  float* a1 = (float*)((char*)d_ws + (size_t)2 * 1024 * 1024); // 8192 f32
  float* a2 = a1 + 8192;                                       // 8192 f32

  hipMemsetAsync(a1, 0, 2 * 8192 * sizeof(float), stream);
  k1_seqfts<<<256, 256, 0, stream>>>(x, W1, wf1, wf2, FT, a1, a2);
  k2_attn<<<512, 256, 0, stream>>>(adj, FT, a1, a2, b1, b2, out);
}